// Round 1
// baseline (5839.328 us; speedup 1.0000x reference)
//
#include <hip/hip_runtime.h>
#include <hip/hip_bf16.h>
#include <math.h>

#define NN 100000
#define NE 1600000
// dims: D_IN = HID = 128, E_CH = 16

typedef __bf16 bf16x8 __attribute__((ext_vector_type(8)));
typedef float f32x4 __attribute__((ext_vector_type(4)));

union BF8 { bf16x8 v; unsigned short u[8]; };

static __device__ __forceinline__ unsigned short f2bf(float f) {
  unsigned int u = __float_as_uint(f);
  unsigned int r = u + 0x7fffu + ((u >> 16) & 1u);   // RNE
  return (unsigned short)(r >> 16);
}
static __device__ __forceinline__ f32x4 zero4() {
  f32x4 z = {0.f, 0.f, 0.f, 0.f}; return z;
}
static __device__ __forceinline__ bf16x8 zerobf8() {
  BF8 t;
  #pragma unroll
  for (int j = 0; j < 8; ++j) t.u[j] = 0;
  return t.v;
}
static __device__ __forceinline__ bf16x8 cvt8(float4 v0, float4 v1, float s) {
  BF8 t;
  t.u[0]=f2bf(v0.x*s); t.u[1]=f2bf(v0.y*s); t.u[2]=f2bf(v0.z*s); t.u[3]=f2bf(v0.w*s);
  t.u[4]=f2bf(v1.x*s); t.u[5]=f2bf(v1.y*s); t.u[6]=f2bf(v1.z*s); t.u[7]=f2bf(v1.w*s);
  return t.v;
}

// ---------------------------------------------------------------------------
// Pre-swizzle weights into B-fragment order (bf16):
//   swz[((t*KC + c)*64 + lane)*8 + j] = W[k][n],  k = c*32 + (lane>>4)*8 + j,
//                                                 n = t*16 + (lane&15)
// regions: [0)      nodeW0 (Wl0|Wr0 stacked, K=256,N=128)  32768
//          [32768)  nodeW1                                  32768
//          [65536)  Wc1 (K=272 pad 288, N=128)              36864
//          [102400) Wc2 (K=128, N=64)                        8192
// total 110592
__global__ void prep_swizzle(const float* __restrict__ Wl0, const float* __restrict__ Wr0,
                             const float* __restrict__ Wl1, const float* __restrict__ Wr1,
                             const float* __restrict__ Wc1, const float* __restrict__ Wc2,
                             __hip_bfloat16* __restrict__ swz) {
  int gid = blockIdx.x * 256 + threadIdx.x;
  if (gid >= 110592) return;
  int id = gid;
  const float* A; const float* B = nullptr; int KC, Nc, Ksrc;
  if (id < 32768)        { KC = 8; Nc = 128; Ksrc = 256; A = Wl0; B = Wr0; }
  else if (id < 65536)   { id -= 32768; KC = 8; Nc = 128; Ksrc = 256; A = Wl1; B = Wr1; }
  else if (id < 102400)  { id -= 65536; KC = 9; Nc = 128; Ksrc = 272; A = Wc1; }
  else                   { id -= 102400; KC = 4; Nc = 64;  Ksrc = 128; A = Wc2; }
  int j = id & 7, lane = (id >> 3) & 63, rest = id >> 9;
  int c = rest % KC, t = rest / KC;
  int k = c * 32 + (lane >> 4) * 8 + j;
  int n = t * 16 + (lane & 15);
  float v = 0.f;
  if (k < Ksrc) {
    if (B && k >= 128) v = B[(k - 128) * Nc + n];
    else               v = A[k * Nc + n];
  }
  unsigned short* o = (unsigned short*)swz;
  o[gid] = f2bf(v);
}

// ---------------------------------------------------------------------------
// scatter-add:  msg[dst] += feat[src]   (+ degree on layer 0)
// one thread per (edge, 4-channel group): gid = e*32 + q
__global__ void scatter_k(const float* __restrict__ xf,
                          const __hip_bfloat16* __restrict__ xb,
                          const int* __restrict__ ei,
                          float* __restrict__ msg, float* __restrict__ deg, int addDeg) {
  int gid = blockIdx.x * 256 + threadIdx.x;
  int e = gid >> 5, q = gid & 31;
  int s = ei[e], d = ei[NE + e];
  float v0, v1, v2, v3;
  if (xf) {
    float4 v = *(const float4*)(xf + (size_t)s * 128 + q * 4);
    v0 = v.x; v1 = v.y; v2 = v.z; v3 = v.w;
  } else {
    ushort4 u = *(const ushort4*)(xb + (size_t)s * 128 + q * 4);
    v0 = __uint_as_float((unsigned)u.x << 16);
    v1 = __uint_as_float((unsigned)u.y << 16);
    v2 = __uint_as_float((unsigned)u.z << 16);
    v3 = __uint_as_float((unsigned)u.w << 16);
  }
  float* m = msg + (size_t)d * 128 + q * 4;
  atomicAdd(m + 0, v0); atomicAdd(m + 1, v1);
  atomicAdd(m + 2, v2); atomicAdd(m + 3, v3);
  if (addDeg && q == 0) atomicAdd(deg + d, 1.0f);
}

// ---------------------------------------------------------------------------
// node GEMM: h[n] = relu([msg[n]/deg | self[n]] @ [Wl;Wr] + b)   -> bf16 out
// 4 waves x 64 nodes/wave; A' = swizzled weights (M=128 chans), B' = node rows
__global__ __launch_bounds__(256, 2)
void node_gemm(const float* __restrict__ msg, const float* __restrict__ deg,
               const float* __restrict__ selfF32, const __hip_bfloat16* __restrict__ selfB16,
               const __hip_bfloat16* __restrict__ swzW, const float* __restrict__ bias,
               __hip_bfloat16* __restrict__ hOut) {
  const int tid = threadIdx.x, w = tid >> 6, lane = tid & 63;
  const int l15 = lane & 15, quad = lane >> 4;
  const int nBase = blockIdx.x * 256 + w * 64;

  int row[4]; float rdeg[4];
  #pragma unroll
  for (int t = 0; t < 4; ++t) {
    int n = nBase + t * 16 + l15;
    if (n > NN - 1) n = NN - 1;
    row[t] = n;
    rdeg[t] = 1.f / fmaxf(deg[n], 1.f);
  }

  f32x4 acc[8][4];
  #pragma unroll
  for (int mt = 0; mt < 8; ++mt)
    #pragma unroll
    for (int nt = 0; nt < 4; ++nt) acc[mt][nt] = zero4();

  #pragma unroll
  for (int c = 0; c < 8; ++c) {
    bf16x8 bfr[4];
    if (c < 4) {
      #pragma unroll
      for (int nt = 0; nt < 4; ++nt) {
        const float4* p = (const float4*)(msg + (size_t)row[nt] * 128 + c * 32 + quad * 8);
        bfr[nt] = cvt8(p[0], p[1], rdeg[nt]);
      }
    } else {
      int cc = (c - 4) * 32 + quad * 8;
      if (selfF32) {
        #pragma unroll
        for (int nt = 0; nt < 4; ++nt) {
          const float4* p = (const float4*)(selfF32 + (size_t)row[nt] * 128 + cc);
          bfr[nt] = cvt8(p[0], p[1], 1.f);
        }
      } else {
        #pragma unroll
        for (int nt = 0; nt < 4; ++nt)
          bfr[nt] = *(const bf16x8*)(selfB16 + (size_t)row[nt] * 128 + cc);
      }
    }
    bf16x8 afr[8];
    #pragma unroll
    for (int mt = 0; mt < 8; ++mt)
      afr[mt] = *(const bf16x8*)(swzW + ((mt * 8 + c) * 64 + lane) * 8);
    #pragma unroll
    for (int mt = 0; mt < 8; ++mt)
      #pragma unroll
      for (int nt = 0; nt < 4; ++nt)
        acc[mt][nt] = __builtin_amdgcn_mfma_f32_16x16x32_bf16(afr[mt], bfr[nt], acc[mt][nt], 0, 0, 0);
  }

  #pragma unroll
  for (int mt = 0; mt < 8; ++mt) {
    const float4 b4 = *(const float4*)(bias + mt * 16 + quad * 4);
    #pragma unroll
    for (int nt = 0; nt < 4; ++nt) {
      int n = nBase + nt * 16 + l15;
      if (n < NN) {
        ushort4 p;
        p.x = f2bf(fmaxf(acc[mt][nt][0] + b4.x, 0.f));
        p.y = f2bf(fmaxf(acc[mt][nt][1] + b4.y, 0.f));
        p.z = f2bf(fmaxf(acc[mt][nt][2] + b4.z, 0.f));
        p.w = f2bf(fmaxf(acc[mt][nt][3] + b4.w, 0.f));
        *(ushort4*)(hOut + (size_t)n * 128 + mt * 16 + quad * 4) = p;
      }
    }
  }
}

// ---------------------------------------------------------------------------
// edge MLP: feat=[h1[src]|h1[dst]|ea] (K=272pad288) @Wc1 relu @Wc2 relu @Wc3 sigmoid
// 4 waves x 64 edges/wave, per-wave private LDS z-buffer, no barriers.
__global__ __launch_bounds__(256, 2)
void edge_mlp(const __hip_bfloat16* __restrict__ h1, const int* __restrict__ ei,
              const float* __restrict__ ea,
              const __hip_bfloat16* __restrict__ swzWc1, const __hip_bfloat16* __restrict__ swzWc2,
              const float* __restrict__ Wc3, const float* __restrict__ bc1,
              const float* __restrict__ bc2, const float* __restrict__ bc3,
              float* __restrict__ out) {
  __shared__ char lds[4 * 64 * 288];   // 73728 B: per-wave 18432 B
  const int tid = threadIdx.x, w = tid >> 6, lane = tid & 63;
  const int l15 = lane & 15, quad = lane >> 4;
  const int eBase = blockIdx.x * 256 + w * 64;
  char* zbuf = lds + w * (64 * 288);

  int eRow[4], srcOff[4], dstOff[4];
  #pragma unroll
  for (int t = 0; t < 4; ++t) {
    int e = eBase + t * 16 + l15;
    eRow[t] = e;
    srcOff[t] = ei[e] * 128;
    dstOff[t] = ei[NE + e] * 128;
  }

  // ---- layer 1: z1^T = Wc1^T @ feat^T, acc[chan-tile][edge-tile]
  f32x4 acc[8][4];
  #pragma unroll
  for (int mt = 0; mt < 8; ++mt)
    #pragma unroll
    for (int nt = 0; nt < 4; ++nt) acc[mt][nt] = zero4();

  #pragma unroll
  for (int c = 0; c < 9; ++c) {
    bf16x8 bfr[4];
    if (c < 4) {
      #pragma unroll
      for (int nt = 0; nt < 4; ++nt)
        bfr[nt] = *(const bf16x8*)(h1 + srcOff[nt] + c * 32 + quad * 8);
    } else if (c < 8) {
      #pragma unroll
      for (int nt = 0; nt < 4; ++nt)
        bfr[nt] = *(const bf16x8*)(h1 + dstOff[nt] + (c - 4) * 32 + quad * 8);
    } else {
      #pragma unroll
      for (int nt = 0; nt < 4; ++nt) {
        if (quad < 2) {
          const float4* p = (const float4*)(ea + (size_t)eRow[nt] * 16 + quad * 8);
          bfr[nt] = cvt8(p[0], p[1], 1.f);
        } else {
          bfr[nt] = zerobf8();
        }
      }
    }
    bf16x8 afr[8];
    #pragma unroll
    for (int mt = 0; mt < 8; ++mt)
      afr[mt] = *(const bf16x8*)(swzWc1 + ((mt * 9 + c) * 64 + lane) * 8);
    #pragma unroll
    for (int mt = 0; mt < 8; ++mt)
      #pragma unroll
      for (int nt = 0; nt < 4; ++nt)
        acc[mt][nt] = __builtin_amdgcn_mfma_f32_16x16x32_bf16(afr[mt], bfr[nt], acc[mt][nt], 0, 0, 0);
  }

  // epilogue -> z1 row-major [64 edge][128 chan], row stride 288 B
  #pragma unroll
  for (int mt = 0; mt < 8; ++mt) {
    const float4 b4 = *(const float4*)(bc1 + mt * 16 + quad * 4);
    #pragma unroll
    for (int nt = 0; nt < 4; ++nt) {
      int er = nt * 16 + l15;
      ushort4 p;
      p.x = f2bf(fmaxf(acc[mt][nt][0] + b4.x, 0.f));
      p.y = f2bf(fmaxf(acc[mt][nt][1] + b4.y, 0.f));
      p.z = f2bf(fmaxf(acc[mt][nt][2] + b4.z, 0.f));
      p.w = f2bf(fmaxf(acc[mt][nt][3] + b4.w, 0.f));
      *(ushort4*)(zbuf + er * 288 + (mt * 16 + quad * 4) * 2) = p;
    }
  }

  // ---- layer 2: z2^T = Wc2^T @ z1^T  (K=128, N chans 64)
  f32x4 acc2[4][4];
  #pragma unroll
  for (int mt = 0; mt < 4; ++mt)
    #pragma unroll
    for (int nt = 0; nt < 4; ++nt) acc2[mt][nt] = zero4();

  #pragma unroll
  for (int c = 0; c < 4; ++c) {
    bf16x8 bfr[4];
    #pragma unroll
    for (int nt = 0; nt < 4; ++nt)
      bfr[nt] = *(const bf16x8*)(zbuf + (nt * 16 + l15) * 288 + (c * 32 + quad * 8) * 2);
    bf16x8 afr[4];
    #pragma unroll
    for (int mt = 0; mt < 4; ++mt)
      afr[mt] = *(const bf16x8*)(swzWc2 + ((mt * 4 + c) * 64 + lane) * 8);
    #pragma unroll
    for (int mt = 0; mt < 4; ++mt)
      #pragma unroll
      for (int nt = 0; nt < 4; ++nt)
        acc2[mt][nt] = __builtin_amdgcn_mfma_f32_16x16x32_bf16(afr[mt], bfr[nt], acc2[mt][nt], 0, 0, 0);
  }

  // epilogue -> z2 row-major [64 edge][64 chan], row stride 272 B (overwrites z1, reads done)
  #pragma unroll
  for (int mt = 0; mt < 4; ++mt) {
    const float4 b4 = *(const float4*)(bc2 + mt * 16 + quad * 4);
    #pragma unroll
    for (int nt = 0; nt < 4; ++nt) {
      int er = nt * 16 + l15;
      ushort4 p;
      p.x = f2bf(fmaxf(acc2[mt][nt][0] + b4.x, 0.f));
      p.y = f2bf(fmaxf(acc2[mt][nt][1] + b4.y, 0.f));
      p.z = f2bf(fmaxf(acc2[mt][nt][2] + b4.z, 0.f));
      p.w = f2bf(fmaxf(acc2[mt][nt][3] + b4.w, 0.f));
      *(ushort4*)(zbuf + er * 272 + (mt * 16 + quad * 4) * 2) = p;
    }
  }

  // ---- layer 3: per-lane dot(z2[row], Wc3) + bc3, sigmoid
  float a3 = bc3[0];
  #pragma unroll
  for (int k2 = 0; k2 < 32; ++k2) {
    unsigned int u = *(const unsigned int*)(zbuf + lane * 272 + k2 * 4);
    float v0 = __uint_as_float(u << 16);
    float v1 = __uint_as_float(u & 0xffff0000u);
    a3 += v0 * Wc3[2 * k2] + v1 * Wc3[2 * k2 + 1];
  }
  out[eBase + lane] = 1.f / (1.f + __expf(-a3));
}

// ---------------------------------------------------------------------------
extern "C" void kernel_launch(void* const* d_in, const int* in_sizes, int n_in,
                              void* d_out, int out_size, void* d_ws, size_t ws_size,
                              hipStream_t stream) {
  const float* x   = (const float*)d_in[0];
  const int*   ei  = (const int*)d_in[1];
  const float* ea  = (const float*)d_in[2];
  const float* Wl0 = (const float*)d_in[3];
  const float* Wr0 = (const float*)d_in[4];
  const float* b0  = (const float*)d_in[5];
  const float* Wl1 = (const float*)d_in[6];
  const float* Wr1 = (const float*)d_in[7];
  const float* b1  = (const float*)d_in[8];
  const float* Wc1 = (const float*)d_in[9];
  const float* bc1 = (const float*)d_in[10];
  const float* Wc2 = (const float*)d_in[11];
  const float* bc2 = (const float*)d_in[12];
  const float* Wc3 = (const float*)d_in[13];
  const float* bc3 = (const float*)d_in[14];
  float* out = (float*)d_out;

  char* ws = (char*)d_ws;
  float* deg = (float*)ws;                                   //      400,000 B
  float* msg = (float*)(ws + 400000);                        //   51,200,000 B
  __hip_bfloat16* h0b = (__hip_bfloat16*)(ws + 51600000);    //   25,600,000 B
  __hip_bfloat16* h1b = h0b + (size_t)NN * 128;              //   25,600,000 B
  __hip_bfloat16* swz = h1b + (size_t)NN * 128;              //      221,184 B

  // zero deg+msg (contiguous)
  hipMemsetAsync(d_ws, 0, 51600000, stream);
  prep_swizzle<<<432, 256, 0, stream>>>(Wl0, Wr0, Wl1, Wr1, Wc1, Wc2, swz);

  // layer 0
  scatter_k<<<NE * 32 / 256, 256, 0, stream>>>(x, nullptr, ei, msg, deg, 1);
  node_gemm<<<(NN + 255) / 256, 256, 0, stream>>>(msg, deg, x, nullptr, swz, b0, h0b);

  // layer 1
  hipMemsetAsync(msg, 0, 51200000, stream);
  scatter_k<<<NE * 32 / 256, 256, 0, stream>>>(nullptr, h0b, ei, msg, deg, 0);
  node_gemm<<<(NN + 255) / 256, 256, 0, stream>>>(msg, deg, nullptr, h0b, swz + 32768, b1, h1b);

  // edge classifier
  edge_mlp<<<NE / 256, 256, 0, stream>>>(h1b, ei, ea, swz + 65536, swz + 102400,
                                         Wc3, bc1, bc2, bc3, out);
}

// Round 2
// 1010.253 us; speedup vs baseline: 5.7801x; 5.7801x over previous
//
#include <hip/hip_runtime.h>
#include <hip/hip_bf16.h>
#include <math.h>

#define NN 100000
#define NE 1600000
#define NBLK 391   // ceil(NN/256)
// dims: D_IN = HID = 128, E_CH = 16

typedef __bf16 bf16x8 __attribute__((ext_vector_type(8)));
typedef float f32x4 __attribute__((ext_vector_type(4)));

union BF8 { bf16x8 v; unsigned short u[8]; };

static __device__ __forceinline__ unsigned short f2bf(float f) {
  unsigned int u = __float_as_uint(f);
  unsigned int r = u + 0x7fffu + ((u >> 16) & 1u);   // RNE
  return (unsigned short)(r >> 16);
}
static __device__ __forceinline__ f32x4 zero4() {
  f32x4 z = {0.f, 0.f, 0.f, 0.f}; return z;
}
static __device__ __forceinline__ bf16x8 zerobf8() {
  BF8 t;
  #pragma unroll
  for (int j = 0; j < 8; ++j) t.u[j] = 0;
  return t.v;
}
static __device__ __forceinline__ bf16x8 cvt8(float4 v0, float4 v1, float s) {
  BF8 t;
  t.u[0]=f2bf(v0.x*s); t.u[1]=f2bf(v0.y*s); t.u[2]=f2bf(v0.z*s); t.u[3]=f2bf(v0.w*s);
  t.u[4]=f2bf(v1.x*s); t.u[5]=f2bf(v1.y*s); t.u[6]=f2bf(v1.z*s); t.u[7]=f2bf(v1.w*s);
  return t.v;
}

// ---------------------------------------------------------------------------
// Pre-swizzle weights into B-fragment order (bf16):
//   swz[((t*KC + c)*64 + lane)*8 + j] = W[k][n],  k = c*32 + (lane>>4)*8 + j,
//                                                 n = t*16 + (lane&15)
// regions: [0)      nodeW0 (Wl0|Wr0 stacked, K=256,N=128)  32768
//          [32768)  nodeW1                                  32768
//          [65536)  Wc1 (K=272 pad 288, N=128)              36864
//          [102400) Wc2 (K=128, N=64)                        8192
__global__ void prep_swizzle(const float* __restrict__ Wl0, const float* __restrict__ Wr0,
                             const float* __restrict__ Wl1, const float* __restrict__ Wr1,
                             const float* __restrict__ Wc1, const float* __restrict__ Wc2,
                             __hip_bfloat16* __restrict__ swz) {
  int gid = blockIdx.x * 256 + threadIdx.x;
  if (gid >= 110592) return;
  int id = gid;
  const float* A; const float* B = nullptr; int KC, Nc, Ksrc;
  if (id < 32768)        { KC = 8; Nc = 128; Ksrc = 256; A = Wl0; B = Wr0; }
  else if (id < 65536)   { id -= 32768; KC = 8; Nc = 128; Ksrc = 256; A = Wl1; B = Wr1; }
  else if (id < 102400)  { id -= 65536; KC = 9; Nc = 128; Ksrc = 272; A = Wc1; }
  else                   { id -= 102400; KC = 4; Nc = 64;  Ksrc = 128; A = Wc2; }
  int j = id & 7, lane = (id >> 3) & 63, rest = id >> 9;
  int c = rest % KC, t = rest / KC;
  int k = c * 32 + (lane >> 4) * 8 + j;
  int n = t * 16 + (lane & 15);
  float v = 0.f;
  if (k < Ksrc) {
    if (B && k >= 128) v = B[(k - 128) * Nc + n];
    else               v = A[k * Nc + n];
  }
  unsigned short* o = (unsigned short*)swz;
  o[gid] = f2bf(v);
}

// ---------------------------------------------------------------------------
// CSR build: count degrees, scan, fill
__global__ void deg_count(const int* __restrict__ ei, int* __restrict__ degCnt) {
  int e = blockIdx.x * 256 + threadIdx.x;
  atomicAdd(&degCnt[ei[NE + e]], 1);
}

__global__ void scan_block_sums(const int* __restrict__ degCnt, int* __restrict__ blockSums) {
  __shared__ int red[4];
  int i = blockIdx.x * 256 + threadIdx.x;
  int v = (i < NN) ? degCnt[i] : 0;
  #pragma unroll
  for (int off = 32; off; off >>= 1) v += __shfl_down(v, off, 64);
  if ((threadIdx.x & 63) == 0) red[threadIdx.x >> 6] = v;
  __syncthreads();
  if (threadIdx.x == 0) blockSums[blockIdx.x] = red[0] + red[1] + red[2] + red[3];
}

__global__ void scan_partials(const int* __restrict__ blockSums, int* __restrict__ blockOff) {
  __shared__ int lds[512];
  int t = threadIdx.x;
  int v = (t < NBLK) ? blockSums[t] : 0;
  lds[t] = v; __syncthreads();
  #pragma unroll
  for (int off = 1; off < 512; off <<= 1) {
    int a = (t >= off) ? lds[t - off] : 0;
    __syncthreads();
    lds[t] += a;
    __syncthreads();
  }
  if (t < NBLK) blockOff[t] = lds[t] - v;   // exclusive
}

__global__ void scan_write(const int* __restrict__ degCnt, const int* __restrict__ blockOff,
                           int* __restrict__ rowPtr, int* __restrict__ cursor) {
  __shared__ int lds[256];
  int t = threadIdx.x;
  int i = blockIdx.x * 256 + t;
  int v = (i < NN) ? degCnt[i] : 0;
  lds[t] = v; __syncthreads();
  #pragma unroll
  for (int off = 1; off < 256; off <<= 1) {
    int a = (t >= off) ? lds[t - off] : 0;
    __syncthreads();
    lds[t] += a;
    __syncthreads();
  }
  if (i < NN) {
    int excl = blockOff[blockIdx.x] + lds[t] - v;
    rowPtr[i] = excl;
    cursor[i] = excl;
  }
}

__global__ void csr_fill(const int* __restrict__ ei, int* __restrict__ cursor,
                         int* __restrict__ csrSrc) {
  int e = blockIdx.x * 256 + threadIdx.x;
  int s = ei[e], d = ei[NE + e];
  int idx = atomicAdd(&cursor[d], 1);
  csrSrc[idx] = s;
}

// ---------------------------------------------------------------------------
// gather-mean: msgOut[n] = mean over neighbors s of feat[s]  (bf16 out)
// 64 threads per node (2 channels each), 4 nodes per block. No atomics.
__global__ __launch_bounds__(256, 8)
void gather_agg(const float* __restrict__ xf, const __hip_bfloat16* __restrict__ xb,
                const int* __restrict__ csrSrc, const int* __restrict__ rowPtr,
                const int* __restrict__ degCnt, __hip_bfloat16* __restrict__ msgOut) {
  int n = blockIdx.x * 4 + (threadIdx.x >> 6);
  int c2 = threadIdx.x & 63;               // channel pair
  if (n >= NN) return;
  int rp = rowPtr[n], dg = degCnt[n];
  float acc0 = 0.f, acc1 = 0.f;
  if (xf) {
    for (int i = 0; i < dg; ++i) {
      int s = csrSrc[rp + i];
      float2 v = *(const float2*)(xf + (size_t)s * 128 + c2 * 2);
      acc0 += v.x; acc1 += v.y;
    }
  } else {
    for (int i = 0; i < dg; ++i) {
      int s = csrSrc[rp + i];
      unsigned int u = *(const unsigned int*)(xb + (size_t)s * 128 + c2 * 2);
      acc0 += __uint_as_float(u << 16);
      acc1 += __uint_as_float(u & 0xffff0000u);
    }
  }
  float r = 1.f / fmaxf((float)dg, 1.f);
  unsigned int p = (unsigned int)f2bf(acc0 * r) | ((unsigned int)f2bf(acc1 * r) << 16);
  *(unsigned int*)((unsigned short*)msgOut + (size_t)n * 128 + c2 * 2) = p;
}

// ---------------------------------------------------------------------------
// node GEMM: h[n] = relu([mean | self[n]] @ [Wl;Wr] + b)   -> bf16 out
// 4 waves x 64 nodes/wave; A' = swizzled weights (M=128 chans), B' = node rows
__global__ __launch_bounds__(256, 2)
void node_gemm(const __hip_bfloat16* __restrict__ msgB,
               const float* __restrict__ selfF32, const __hip_bfloat16* __restrict__ selfB16,
               const __hip_bfloat16* __restrict__ swzW, const float* __restrict__ bias,
               __hip_bfloat16* __restrict__ hOut) {
  const int tid = threadIdx.x, w = tid >> 6, lane = tid & 63;
  const int l15 = lane & 15, quad = lane >> 4;
  const int nBase = blockIdx.x * 256 + w * 64;

  int row[4];
  #pragma unroll
  for (int t = 0; t < 4; ++t) {
    int n = nBase + t * 16 + l15;
    if (n > NN - 1) n = NN - 1;
    row[t] = n;
  }

  f32x4 acc[8][4];
  #pragma unroll
  for (int mt = 0; mt < 8; ++mt)
    #pragma unroll
    for (int nt = 0; nt < 4; ++nt) acc[mt][nt] = zero4();

  #pragma unroll
  for (int c = 0; c < 8; ++c) {
    bf16x8 bfr[4];
    if (c < 4) {
      #pragma unroll
      for (int nt = 0; nt < 4; ++nt)
        bfr[nt] = *(const bf16x8*)(msgB + (size_t)row[nt] * 128 + c * 32 + quad * 8);
    } else {
      int cc = (c - 4) * 32 + quad * 8;
      if (selfF32) {
        #pragma unroll
        for (int nt = 0; nt < 4; ++nt) {
          const float4* p = (const float4*)(selfF32 + (size_t)row[nt] * 128 + cc);
          bfr[nt] = cvt8(p[0], p[1], 1.f);
        }
      } else {
        #pragma unroll
        for (int nt = 0; nt < 4; ++nt)
          bfr[nt] = *(const bf16x8*)(selfB16 + (size_t)row[nt] * 128 + cc);
      }
    }
    bf16x8 afr[8];
    #pragma unroll
    for (int mt = 0; mt < 8; ++mt)
      afr[mt] = *(const bf16x8*)(swzW + ((mt * 8 + c) * 64 + lane) * 8);
    #pragma unroll
    for (int mt = 0; mt < 8; ++mt)
      #pragma unroll
      for (int nt = 0; nt < 4; ++nt)
        acc[mt][nt] = __builtin_amdgcn_mfma_f32_16x16x32_bf16(afr[mt], bfr[nt], acc[mt][nt], 0, 0, 0);
  }

  #pragma unroll
  for (int mt = 0; mt < 8; ++mt) {
    const float4 b4 = *(const float4*)(bias + mt * 16 + quad * 4);
    #pragma unroll
    for (int nt = 0; nt < 4; ++nt) {
      int n = nBase + nt * 16 + l15;
      if (n < NN) {
        ushort4 p;
        p.x = f2bf(fmaxf(acc[mt][nt][0] + b4.x, 0.f));
        p.y = f2bf(fmaxf(acc[mt][nt][1] + b4.y, 0.f));
        p.z = f2bf(fmaxf(acc[mt][nt][2] + b4.z, 0.f));
        p.w = f2bf(fmaxf(acc[mt][nt][3] + b4.w, 0.f));
        *(ushort4*)(hOut + (size_t)n * 128 + mt * 16 + quad * 4) = p;
      }
    }
  }
}

// ---------------------------------------------------------------------------
// edge MLP: feat=[h1[src]|h1[dst]|ea] (K=272pad288) @Wc1 relu @Wc2 relu @Wc3 sigmoid
// 4 waves x 64 edges/wave, per-wave private LDS z-buffer, no barriers.
__global__ __launch_bounds__(256, 2)
void edge_mlp(const __hip_bfloat16* __restrict__ h1, const int* __restrict__ ei,
              const float* __restrict__ ea,
              const __hip_bfloat16* __restrict__ swzWc1, const __hip_bfloat16* __restrict__ swzWc2,
              const float* __restrict__ Wc3, const float* __restrict__ bc1,
              const float* __restrict__ bc2, const float* __restrict__ bc3,
              float* __restrict__ out) {
  __shared__ char lds[4 * 64 * 288];   // 73728 B: per-wave 18432 B
  const int tid = threadIdx.x, w = tid >> 6, lane = tid & 63;
  const int l15 = lane & 15, quad = lane >> 4;
  const int eBase = blockIdx.x * 256 + w * 64;
  char* zbuf = lds + w * (64 * 288);

  int eRow[4], srcOff[4], dstOff[4];
  #pragma unroll
  for (int t = 0; t < 4; ++t) {
    int e = eBase + t * 16 + l15;
    eRow[t] = e;
    srcOff[t] = ei[e] * 128;
    dstOff[t] = ei[NE + e] * 128;
  }

  // ---- layer 1: z1^T = Wc1^T @ feat^T, acc[chan-tile][edge-tile]
  f32x4 acc[8][4];
  #pragma unroll
  for (int mt = 0; mt < 8; ++mt)
    #pragma unroll
    for (int nt = 0; nt < 4; ++nt) acc[mt][nt] = zero4();

  #pragma unroll
  for (int c = 0; c < 9; ++c) {
    bf16x8 bfr[4];
    if (c < 4) {
      #pragma unroll
      for (int nt = 0; nt < 4; ++nt)
        bfr[nt] = *(const bf16x8*)(h1 + srcOff[nt] + c * 32 + quad * 8);
    } else if (c < 8) {
      #pragma unroll
      for (int nt = 0; nt < 4; ++nt)
        bfr[nt] = *(const bf16x8*)(h1 + dstOff[nt] + (c - 4) * 32 + quad * 8);
    } else {
      #pragma unroll
      for (int nt = 0; nt < 4; ++nt) {
        if (quad < 2) {
          const float4* p = (const float4*)(ea + (size_t)eRow[nt] * 16 + quad * 8);
          bfr[nt] = cvt8(p[0], p[1], 1.f);
        } else {
          bfr[nt] = zerobf8();
        }
      }
    }
    bf16x8 afr[8];
    #pragma unroll
    for (int mt = 0; mt < 8; ++mt)
      afr[mt] = *(const bf16x8*)(swzWc1 + ((mt * 9 + c) * 64 + lane) * 8);
    #pragma unroll
    for (int mt = 0; mt < 8; ++mt)
      #pragma unroll
      for (int nt = 0; nt < 4; ++nt)
        acc[mt][nt] = __builtin_amdgcn_mfma_f32_16x16x32_bf16(afr[mt], bfr[nt], acc[mt][nt], 0, 0, 0);
  }

  // epilogue -> z1 row-major [64 edge][128 chan], row stride 288 B
  #pragma unroll
  for (int mt = 0; mt < 8; ++mt) {
    const float4 b4 = *(const float4*)(bc1 + mt * 16 + quad * 4);
    #pragma unroll
    for (int nt = 0; nt < 4; ++nt) {
      int er = nt * 16 + l15;
      ushort4 p;
      p.x = f2bf(fmaxf(acc[mt][nt][0] + b4.x, 0.f));
      p.y = f2bf(fmaxf(acc[mt][nt][1] + b4.y, 0.f));
      p.z = f2bf(fmaxf(acc[mt][nt][2] + b4.z, 0.f));
      p.w = f2bf(fmaxf(acc[mt][nt][3] + b4.w, 0.f));
      *(ushort4*)(zbuf + er * 288 + (mt * 16 + quad * 4) * 2) = p;
    }
  }

  // ---- layer 2: z2^T = Wc2^T @ z1^T  (K=128, N chans 64)
  f32x4 acc2[4][4];
  #pragma unroll
  for (int mt = 0; mt < 4; ++mt)
    #pragma unroll
    for (int nt = 0; nt < 4; ++nt) acc2[mt][nt] = zero4();

  #pragma unroll
  for (int c = 0; c < 4; ++c) {
    bf16x8 bfr[4];
    #pragma unroll
    for (int nt = 0; nt < 4; ++nt)
      bfr[nt] = *(const bf16x8*)(zbuf + (nt * 16 + l15) * 288 + (c * 32 + quad * 8) * 2);
    bf16x8 afr[4];
    #pragma unroll
    for (int mt = 0; mt < 4; ++mt)
      afr[mt] = *(const bf16x8*)(swzWc2 + ((mt * 4 + c) * 64 + lane) * 8);
    #pragma unroll
    for (int mt = 0; mt < 4; ++mt)
      #pragma unroll
      for (int nt = 0; nt < 4; ++nt)
        acc2[mt][nt] = __builtin_amdgcn_mfma_f32_16x16x32_bf16(afr[mt], bfr[nt], acc2[mt][nt], 0, 0, 0);
  }

  // epilogue -> z2 row-major [64 edge][64 chan], row stride 272 B (overwrites z1, reads done)
  #pragma unroll
  for (int mt = 0; mt < 4; ++mt) {
    const float4 b4 = *(const float4*)(bc2 + mt * 16 + quad * 4);
    #pragma unroll
    for (int nt = 0; nt < 4; ++nt) {
      int er = nt * 16 + l15;
      ushort4 p;
      p.x = f2bf(fmaxf(acc2[mt][nt][0] + b4.x, 0.f));
      p.y = f2bf(fmaxf(acc2[mt][nt][1] + b4.y, 0.f));
      p.z = f2bf(fmaxf(acc2[mt][nt][2] + b4.z, 0.f));
      p.w = f2bf(fmaxf(acc2[mt][nt][3] + b4.w, 0.f));
      *(ushort4*)(zbuf + er * 272 + (mt * 16 + quad * 4) * 2) = p;
    }
  }

  // ---- layer 3: per-lane dot(z2[row], Wc3) + bc3, sigmoid
  float a3 = bc3[0];
  #pragma unroll
  for (int k2 = 0; k2 < 32; ++k2) {
    unsigned int u = *(const unsigned int*)(zbuf + lane * 272 + k2 * 4);
    float v0 = __uint_as_float(u << 16);
    float v1 = __uint_as_float(u & 0xffff0000u);
    a3 += v0 * Wc3[2 * k2] + v1 * Wc3[2 * k2 + 1];
  }
  out[eBase + lane] = 1.f / (1.f + __expf(-a3));
}

// ---------------------------------------------------------------------------
extern "C" void kernel_launch(void* const* d_in, const int* in_sizes, int n_in,
                              void* d_out, int out_size, void* d_ws, size_t ws_size,
                              hipStream_t stream) {
  const float* x   = (const float*)d_in[0];
  const int*   ei  = (const int*)d_in[1];
  const float* ea  = (const float*)d_in[2];
  const float* Wl0 = (const float*)d_in[3];
  const float* Wr0 = (const float*)d_in[4];
  const float* b0  = (const float*)d_in[5];
  const float* Wl1 = (const float*)d_in[6];
  const float* Wr1 = (const float*)d_in[7];
  const float* b1  = (const float*)d_in[8];
  const float* Wc1 = (const float*)d_in[9];
  const float* bc1 = (const float*)d_in[10];
  const float* Wc2 = (const float*)d_in[11];
  const float* bc2 = (const float*)d_in[12];
  const float* Wc3 = (const float*)d_in[13];
  const float* bc3 = (const float*)d_in[14];
  float* out = (float*)d_out;

  char* ws = (char*)d_ws;
  int* degCnt   = (int*)(ws + 0);                            //   400,000 B
  int* rowPtr   = (int*)(ws + 400000);                       //   400,000 B
  int* cursor   = (int*)(ws + 800000);                       //   400,000 B
  int* blockSums= (int*)(ws + 1200000);                      //     2,048 B
  int* blockOff = (int*)(ws + 1202048);                      //     2,048 B
  int* csrSrc   = (int*)(ws + 1204096);                      // 6,400,000 B
  __hip_bfloat16* msgB = (__hip_bfloat16*)(ws + 7604096);    // 25,600,000 B
  __hip_bfloat16* h0b  = (__hip_bfloat16*)(ws + 33204096);   // 25,600,000 B
  __hip_bfloat16* h1b  = (__hip_bfloat16*)(ws + 58804096);   // 25,600,000 B
  __hip_bfloat16* swz  = (__hip_bfloat16*)(ws + 84404096);   //    221,184 B
  // total 84,625,280 B

  hipMemsetAsync(degCnt, 0, 400000, stream);
  prep_swizzle<<<432, 256, 0, stream>>>(Wl0, Wr0, Wl1, Wr1, Wc1, Wc2, swz);

  // CSR build (once, reused by both layers)
  deg_count<<<NE / 256, 256, 0, stream>>>(ei, degCnt);
  scan_block_sums<<<NBLK, 256, 0, stream>>>(degCnt, blockSums);
  scan_partials<<<1, 512, 0, stream>>>(blockSums, blockOff);
  scan_write<<<NBLK, 256, 0, stream>>>(degCnt, blockOff, rowPtr, cursor);
  csr_fill<<<NE / 256, 256, 0, stream>>>(ei, cursor, csrSrc);

  // layer 0
  gather_agg<<<NN / 4, 256, 0, stream>>>(x, nullptr, csrSrc, rowPtr, degCnt, msgB);
  node_gemm<<<(NN + 255) / 256, 256, 0, stream>>>(msgB, x, nullptr, swz, b0, h0b);

  // layer 1
  gather_agg<<<NN / 4, 256, 0, stream>>>(nullptr, h0b, csrSrc, rowPtr, degCnt, msgB);
  node_gemm<<<(NN + 255) / 256, 256, 0, stream>>>(msgB, nullptr, h0b, swz + 32768, b1, h1b);

  // edge classifier
  edge_mlp<<<NE / 256, 256, 0, stream>>>(h1b, ei, ea, swz + 65536, swz + 102400,
                                         Wc3, bc1, bc2, bc3, out);
}

// Round 3
// 964.689 us; speedup vs baseline: 6.0531x; 1.0472x over previous
//
#include <hip/hip_runtime.h>
#include <hip/hip_bf16.h>
#include <math.h>

#define NN 100000
#define NE 1600000
#define NBLK 391   // ceil(NN/256)
#define ZSTRIDE 296   // z-buffer row stride bytes (74 words, bank-stride 10 -> conflict-free)
// dims: D_IN = HID = 128, E_CH = 16

typedef __bf16 bf16x8 __attribute__((ext_vector_type(8)));
typedef float f32x4 __attribute__((ext_vector_type(4)));

union BF8 { bf16x8 v; unsigned short u[8]; };

static __device__ __forceinline__ unsigned short f2bf(float f) {
  unsigned int u = __float_as_uint(f);
  unsigned int r = u + 0x7fffu + ((u >> 16) & 1u);   // RNE
  return (unsigned short)(r >> 16);
}
static __device__ __forceinline__ f32x4 zero4() {
  f32x4 z = {0.f, 0.f, 0.f, 0.f}; return z;
}
static __device__ __forceinline__ bf16x8 zerobf8() {
  BF8 t;
  #pragma unroll
  for (int j = 0; j < 8; ++j) t.u[j] = 0;
  return t.v;
}
static __device__ __forceinline__ bf16x8 cvt8(float4 v0, float4 v1, float s) {
  BF8 t;
  t.u[0]=f2bf(v0.x*s); t.u[1]=f2bf(v0.y*s); t.u[2]=f2bf(v0.z*s); t.u[3]=f2bf(v0.w*s);
  t.u[4]=f2bf(v1.x*s); t.u[5]=f2bf(v1.y*s); t.u[6]=f2bf(v1.z*s); t.u[7]=f2bf(v1.w*s);
  return t.v;
}

// ---------------------------------------------------------------------------
// Pre-swizzle weights into B-fragment order (bf16):
//   swz[((t*KC + c)*64 + lane)*8 + j] = W[k][n],  k = c*32 + (lane>>4)*8 + j,
//                                                 n = t*16 + (lane&15)
// regions: [0)      nodeW0 (Wl0|Wr0 stacked, K=256,N=128)  32768
//          [32768)  nodeW1                                  32768
//          [65536)  Wc1 (K=272 pad 288, N=128)              36864
//          [102400) Wc2 (K=128, N=64)                        8192
__global__ void prep_swizzle(const float* __restrict__ Wl0, const float* __restrict__ Wr0,
                             const float* __restrict__ Wl1, const float* __restrict__ Wr1,
                             const float* __restrict__ Wc1, const float* __restrict__ Wc2,
                             __hip_bfloat16* __restrict__ swz) {
  int gid = blockIdx.x * 256 + threadIdx.x;
  if (gid >= 110592) return;
  int id = gid;
  const float* A; const float* B = nullptr; int KC, Nc, Ksrc;
  if (id < 32768)        { KC = 8; Nc = 128; Ksrc = 256; A = Wl0; B = Wr0; }
  else if (id < 65536)   { id -= 32768; KC = 8; Nc = 128; Ksrc = 256; A = Wl1; B = Wr1; }
  else if (id < 102400)  { id -= 65536; KC = 9; Nc = 128; Ksrc = 272; A = Wc1; }
  else                   { id -= 102400; KC = 4; Nc = 64;  Ksrc = 128; A = Wc2; }
  int j = id & 7, lane = (id >> 3) & 63, rest = id >> 9;
  int c = rest % KC, t = rest / KC;
  int k = c * 32 + (lane >> 4) * 8 + j;
  int n = t * 16 + (lane & 15);
  float v = 0.f;
  if (k < Ksrc) {
    if (B && k >= 128) v = B[(k - 128) * Nc + n];
    else               v = A[k * Nc + n];
  }
  unsigned short* o = (unsigned short*)swz;
  o[gid] = f2bf(v);
}

// ---------------------------------------------------------------------------
// x (fp32) -> bf16, vectorized
__global__ void x_to_bf16(const float* __restrict__ x, __hip_bfloat16* __restrict__ xb) {
  int i = blockIdx.x * 256 + threadIdx.x;     // one float4 per thread; 3.2M threads
  float4 v = ((const float4*)x)[i];
  ushort4 p;
  p.x = f2bf(v.x); p.y = f2bf(v.y); p.z = f2bf(v.z); p.w = f2bf(v.w);
  ((ushort4*)xb)[i] = p;
}

// ---------------------------------------------------------------------------
// CSR build: count degrees, scan, fill
__global__ void deg_count(const int* __restrict__ ei, int* __restrict__ degCnt) {
  int e = blockIdx.x * 256 + threadIdx.x;
  atomicAdd(&degCnt[ei[NE + e]], 1);
}

__global__ void scan_block_sums(const int* __restrict__ degCnt, int* __restrict__ blockSums) {
  __shared__ int red[4];
  int i = blockIdx.x * 256 + threadIdx.x;
  int v = (i < NN) ? degCnt[i] : 0;
  #pragma unroll
  for (int off = 32; off; off >>= 1) v += __shfl_down(v, off, 64);
  if ((threadIdx.x & 63) == 0) red[threadIdx.x >> 6] = v;
  __syncthreads();
  if (threadIdx.x == 0) blockSums[blockIdx.x] = red[0] + red[1] + red[2] + red[3];
}

__global__ void scan_partials(const int* __restrict__ blockSums, int* __restrict__ blockOff) {
  __shared__ int lds[512];
  int t = threadIdx.x;
  int v = (t < NBLK) ? blockSums[t] : 0;
  lds[t] = v; __syncthreads();
  #pragma unroll
  for (int off = 1; off < 512; off <<= 1) {
    int a = (t >= off) ? lds[t - off] : 0;
    __syncthreads();
    lds[t] += a;
    __syncthreads();
  }
  if (t < NBLK) blockOff[t] = lds[t] - v;   // exclusive
}

__global__ void scan_write(const int* __restrict__ degCnt, const int* __restrict__ blockOff,
                           int* __restrict__ rowPtr, int* __restrict__ cursor) {
  __shared__ int lds[256];
  int t = threadIdx.x;
  int i = blockIdx.x * 256 + t;
  int v = (i < NN) ? degCnt[i] : 0;
  lds[t] = v; __syncthreads();
  #pragma unroll
  for (int off = 1; off < 256; off <<= 1) {
    int a = (t >= off) ? lds[t - off] : 0;
    __syncthreads();
    lds[t] += a;
    __syncthreads();
  }
  if (i < NN) {
    int excl = blockOff[blockIdx.x] + lds[t] - v;
    rowPtr[i] = excl;
    cursor[i] = excl;
  }
}

__global__ void csr_fill(const int* __restrict__ ei, int* __restrict__ cursor,
                         int* __restrict__ csrSrc) {
  int e = blockIdx.x * 256 + threadIdx.x;
  int s = ei[e], d = ei[NE + e];
  int idx = atomicAdd(&cursor[d], 1);
  csrSrc[idx] = s;
}

// ---------------------------------------------------------------------------
// gather-mean: msgOut[n] = mean over neighbors s of feat[s]  (bf16 in, bf16 out)
// one wave per node: half-wave per neighbor (2 rows/iter), 32 lanes x 8B = full row.
__global__ __launch_bounds__(256, 8)
void gather_agg(const __hip_bfloat16* __restrict__ xb,
                const int* __restrict__ csrSrc, const int* __restrict__ rowPtr,
                const int* __restrict__ degCnt, __hip_bfloat16* __restrict__ msgOut) {
  int n = blockIdx.x * 4 + (threadIdx.x >> 6);
  int lane = threadIdx.x & 63;
  int half = lane >> 5;                 // which neighbor of the pair
  int c4 = lane & 31;                   // 4-channel group: chans c4*4 .. +3
  if (n >= NN) return;
  int rp = rowPtr[n], dg = degCnt[n];
  float a0 = 0.f, a1 = 0.f, a2 = 0.f, a3 = 0.f;
  for (int i = half; i < dg; i += 2) {
    int s = csrSrc[rp + i];
    uint2 u = *(const uint2*)((const unsigned short*)xb + (size_t)s * 128 + c4 * 4);
    a0 += __uint_as_float(u.x << 16);
    a1 += __uint_as_float(u.x & 0xffff0000u);
    a2 += __uint_as_float(u.y << 16);
    a3 += __uint_as_float(u.y & 0xffff0000u);
  }
  a0 += __shfl_xor(a0, 32);
  a1 += __shfl_xor(a1, 32);
  a2 += __shfl_xor(a2, 32);
  a3 += __shfl_xor(a3, 32);
  if (half == 0) {
    float r = 1.f / fmaxf((float)dg, 1.f);
    ushort4 p;
    p.x = f2bf(a0 * r); p.y = f2bf(a1 * r);
    p.z = f2bf(a2 * r); p.w = f2bf(a3 * r);
    *(ushort4*)((unsigned short*)msgOut + (size_t)n * 128 + c4 * 4) = p;
  }
}

// ---------------------------------------------------------------------------
// node GEMM: h[n] = relu([mean | self[n]] @ [Wl;Wr] + b)   -> bf16 out
// 4 waves x 64 nodes/wave; A' = swizzled weights (M=128 chans), B' = node rows
__global__ __launch_bounds__(256, 2)
void node_gemm(const __hip_bfloat16* __restrict__ msgB,
               const __hip_bfloat16* __restrict__ selfB16,
               const __hip_bfloat16* __restrict__ swzW, const float* __restrict__ bias,
               __hip_bfloat16* __restrict__ hOut) {
  const int tid = threadIdx.x, w = tid >> 6, lane = tid & 63;
  const int l15 = lane & 15, quad = lane >> 4;
  const int nBase = blockIdx.x * 256 + w * 64;

  int row[4];
  #pragma unroll
  for (int t = 0; t < 4; ++t) {
    int n = nBase + t * 16 + l15;
    if (n > NN - 1) n = NN - 1;
    row[t] = n;
  }

  f32x4 acc[8][4];
  #pragma unroll
  for (int mt = 0; mt < 8; ++mt)
    #pragma unroll
    for (int nt = 0; nt < 4; ++nt) acc[mt][nt] = zero4();

  #pragma unroll
  for (int c = 0; c < 8; ++c) {
    bf16x8 bfr[4];
    if (c < 4) {
      #pragma unroll
      for (int nt = 0; nt < 4; ++nt)
        bfr[nt] = *(const bf16x8*)(msgB + (size_t)row[nt] * 128 + c * 32 + quad * 8);
    } else {
      #pragma unroll
      for (int nt = 0; nt < 4; ++nt)
        bfr[nt] = *(const bf16x8*)(selfB16 + (size_t)row[nt] * 128 + (c - 4) * 32 + quad * 8);
    }
    bf16x8 afr[8];
    #pragma unroll
    for (int mt = 0; mt < 8; ++mt)
      afr[mt] = *(const bf16x8*)(swzW + ((mt * 8 + c) * 64 + lane) * 8);
    #pragma unroll
    for (int mt = 0; mt < 8; ++mt)
      #pragma unroll
      for (int nt = 0; nt < 4; ++nt)
        acc[mt][nt] = __builtin_amdgcn_mfma_f32_16x16x32_bf16(afr[mt], bfr[nt], acc[mt][nt], 0, 0, 0);
  }

  #pragma unroll
  for (int mt = 0; mt < 8; ++mt) {
    const float4 b4 = *(const float4*)(bias + mt * 16 + quad * 4);
    #pragma unroll
    for (int nt = 0; nt < 4; ++nt) {
      int n = nBase + nt * 16 + l15;
      if (n < NN) {
        ushort4 p;
        p.x = f2bf(fmaxf(acc[mt][nt][0] + b4.x, 0.f));
        p.y = f2bf(fmaxf(acc[mt][nt][1] + b4.y, 0.f));
        p.z = f2bf(fmaxf(acc[mt][nt][2] + b4.z, 0.f));
        p.w = f2bf(fmaxf(acc[mt][nt][3] + b4.w, 0.f));
        *(ushort4*)(hOut + (size_t)n * 128 + mt * 16 + quad * 4) = p;
      }
    }
  }
}

// ---------------------------------------------------------------------------
// edge MLP: feat=[h1[src]|h1[dst]|ea] (K=272pad288) @Wc1 relu @Wc2 relu @Wc3 sigmoid
// 4 waves x 32 edges/wave, per-wave private LDS z-buffer (9472 B), no barriers.
// LDS/block = 37888 B -> 4 blocks/CU -> 16 waves/CU.
__global__ __launch_bounds__(256, 4)
void edge_mlp(const __hip_bfloat16* __restrict__ h1, const int* __restrict__ ei,
              const float* __restrict__ ea,
              const __hip_bfloat16* __restrict__ swzWc1, const __hip_bfloat16* __restrict__ swzWc2,
              const float* __restrict__ Wc3, const float* __restrict__ bc1,
              const float* __restrict__ bc2, const float* __restrict__ bc3,
              float* __restrict__ out) {
  __shared__ char lds[4 * 32 * ZSTRIDE];   // 37888 B
  const int tid = threadIdx.x, w = tid >> 6, lane = tid & 63;
  const int l15 = lane & 15, quad = lane >> 4;
  const int eBase = blockIdx.x * 128 + w * 32;
  char* zbuf = lds + w * (32 * ZSTRIDE);

  int eRow[2], srcOff[2], dstOff[2];
  #pragma unroll
  for (int t = 0; t < 2; ++t) {
    int e = eBase + t * 16 + l15;
    eRow[t] = e;
    srcOff[t] = ei[e] * 128;
    dstOff[t] = ei[NE + e] * 128;
  }

  // ---- layer 1: z1^T = Wc1^T @ feat^T, acc[chan-tile][edge-tile]
  f32x4 acc[8][2];
  #pragma unroll
  for (int mt = 0; mt < 8; ++mt)
    #pragma unroll
    for (int nt = 0; nt < 2; ++nt) acc[mt][nt] = zero4();

  #pragma unroll
  for (int c = 0; c < 9; ++c) {
    bf16x8 bfr[2];
    if (c < 4) {
      #pragma unroll
      for (int nt = 0; nt < 2; ++nt)
        bfr[nt] = *(const bf16x8*)(h1 + srcOff[nt] + c * 32 + quad * 8);
    } else if (c < 8) {
      #pragma unroll
      for (int nt = 0; nt < 2; ++nt)
        bfr[nt] = *(const bf16x8*)(h1 + dstOff[nt] + (c - 4) * 32 + quad * 8);
    } else {
      #pragma unroll
      for (int nt = 0; nt < 2; ++nt) {
        if (quad < 2) {
          const float4* p = (const float4*)(ea + (size_t)eRow[nt] * 16 + quad * 8);
          bfr[nt] = cvt8(p[0], p[1], 1.f);
        } else {
          bfr[nt] = zerobf8();
        }
      }
    }
    bf16x8 afr[8];
    #pragma unroll
    for (int mt = 0; mt < 8; ++mt)
      afr[mt] = *(const bf16x8*)(swzWc1 + ((mt * 9 + c) * 64 + lane) * 8);
    #pragma unroll
    for (int mt = 0; mt < 8; ++mt)
      #pragma unroll
      for (int nt = 0; nt < 2; ++nt)
        acc[mt][nt] = __builtin_amdgcn_mfma_f32_16x16x32_bf16(afr[mt], bfr[nt], acc[mt][nt], 0, 0, 0);
  }

  // epilogue -> z1 row-major [32 edge][128 chan], row stride ZSTRIDE
  #pragma unroll
  for (int mt = 0; mt < 8; ++mt) {
    const float4 b4 = *(const float4*)(bc1 + mt * 16 + quad * 4);
    #pragma unroll
    for (int nt = 0; nt < 2; ++nt) {
      int er = nt * 16 + l15;
      ushort4 p;
      p.x = f2bf(fmaxf(acc[mt][nt][0] + b4.x, 0.f));
      p.y = f2bf(fmaxf(acc[mt][nt][1] + b4.y, 0.f));
      p.z = f2bf(fmaxf(acc[mt][nt][2] + b4.z, 0.f));
      p.w = f2bf(fmaxf(acc[mt][nt][3] + b4.w, 0.f));
      *(ushort4*)(zbuf + er * ZSTRIDE + (mt * 16 + quad * 4) * 2) = p;
    }
  }

  // ---- layer 2: z2^T = Wc2^T @ z1^T  (K=128, N chans 64)
  f32x4 acc2[4][2];
  #pragma unroll
  for (int mt = 0; mt < 4; ++mt)
    #pragma unroll
    for (int nt = 0; nt < 2; ++nt) acc2[mt][nt] = zero4();

  #pragma unroll
  for (int c = 0; c < 4; ++c) {
    bf16x8 bfr[2];
    #pragma unroll
    for (int nt = 0; nt < 2; ++nt)
      bfr[nt] = *(const bf16x8*)(zbuf + (nt * 16 + l15) * ZSTRIDE + (c * 32 + quad * 8) * 2);
    bf16x8 afr[4];
    #pragma unroll
    for (int mt = 0; mt < 4; ++mt)
      afr[mt] = *(const bf16x8*)(swzWc2 + ((mt * 4 + c) * 64 + lane) * 8);
    #pragma unroll
    for (int mt = 0; mt < 4; ++mt)
      #pragma unroll
      for (int nt = 0; nt < 2; ++nt)
        acc2[mt][nt] = __builtin_amdgcn_mfma_f32_16x16x32_bf16(afr[mt], bfr[nt], acc2[mt][nt], 0, 0, 0);
  }

  // epilogue -> z2 row-major [32 edge][64 chan], same stride (overwrites z1, reads done)
  #pragma unroll
  for (int mt = 0; mt < 4; ++mt) {
    const float4 b4 = *(const float4*)(bc2 + mt * 16 + quad * 4);
    #pragma unroll
    for (int nt = 0; nt < 2; ++nt) {
      int er = nt * 16 + l15;
      ushort4 p;
      p.x = f2bf(fmaxf(acc2[mt][nt][0] + b4.x, 0.f));
      p.y = f2bf(fmaxf(acc2[mt][nt][1] + b4.y, 0.f));
      p.z = f2bf(fmaxf(acc2[mt][nt][2] + b4.z, 0.f));
      p.w = f2bf(fmaxf(acc2[mt][nt][3] + b4.w, 0.f));
      *(ushort4*)(zbuf + er * ZSTRIDE + (mt * 16 + quad * 4) * 2) = p;
    }
  }

  // ---- layer 3: lane pair per edge (half-wave split over chans), sigmoid
  {
    int e = lane & 31, half = lane >> 5;
    float a3 = (half == 0) ? bc3[0] : 0.f;
    #pragma unroll
    for (int k2 = 0; k2 < 16; ++k2) {
      unsigned int u = *(const unsigned int*)(zbuf + e * ZSTRIDE + half * 64 + k2 * 4);
      float v0 = __uint_as_float(u << 16);
      float v1 = __uint_as_float(u & 0xffff0000u);
      const float2 wv = *(const float2*)(Wc3 + half * 32 + 2 * k2);
      a3 += v0 * wv.x + v1 * wv.y;
    }
    a3 += __shfl_xor(a3, 32);
    if (half == 0)
      out[eBase + e] = 1.f / (1.f + __expf(-a3));
  }
}

// ---------------------------------------------------------------------------
extern "C" void kernel_launch(void* const* d_in, const int* in_sizes, int n_in,
                              void* d_out, int out_size, void* d_ws, size_t ws_size,
                              hipStream_t stream) {
  const float* x   = (const float*)d_in[0];
  const int*   ei  = (const int*)d_in[1];
  const float* ea  = (const float*)d_in[2];
  const float* Wl0 = (const float*)d_in[3];
  const float* Wr0 = (const float*)d_in[4];
  const float* b0  = (const float*)d_in[5];
  const float* Wl1 = (const float*)d_in[6];
  const float* Wr1 = (const float*)d_in[7];
  const float* b1  = (const float*)d_in[8];
  const float* Wc1 = (const float*)d_in[9];
  const float* bc1 = (const float*)d_in[10];
  const float* Wc2 = (const float*)d_in[11];
  const float* bc2 = (const float*)d_in[12];
  const float* Wc3 = (const float*)d_in[13];
  const float* bc3 = (const float*)d_in[14];
  float* out = (float*)d_out;

  char* ws = (char*)d_ws;
  int* degCnt   = (int*)(ws + 0);                            //   400,000 B
  int* rowPtr   = (int*)(ws + 400000);                       //   400,000 B
  int* cursor   = (int*)(ws + 800000);                       //   400,000 B
  int* blockSums= (int*)(ws + 1200000);                      //     2,048 B
  int* blockOff = (int*)(ws + 1202048);                      //     2,048 B
  int* csrSrc   = (int*)(ws + 1204096);                      // 6,400,000 B
  __hip_bfloat16* msgB = (__hip_bfloat16*)(ws + 7604096);    // 25,600,000 B
  __hip_bfloat16* h0b  = (__hip_bfloat16*)(ws + 33204096);   // 25,600,000 B
  __hip_bfloat16* h1b  = (__hip_bfloat16*)(ws + 58804096);   // 25,600,000 B
  __hip_bfloat16* swz  = (__hip_bfloat16*)(ws + 84404096);   //    221,184 B
  // xb (bf16 copy of x) aliases h1b: dead before node_gemm layer-1 writes h1b.
  __hip_bfloat16* xb = h1b;
  // total 84,625,280 B

  hipMemsetAsync(degCnt, 0, 400000, stream);
  prep_swizzle<<<432, 256, 0, stream>>>(Wl0, Wr0, Wl1, Wr1, Wc1, Wc2, swz);
  x_to_bf16<<<12500, 256, 0, stream>>>(x, xb);

  // CSR build (once, reused by both layers)
  deg_count<<<NE / 256, 256, 0, stream>>>(ei, degCnt);
  scan_block_sums<<<NBLK, 256, 0, stream>>>(degCnt, blockSums);
  scan_partials<<<1, 512, 0, stream>>>(blockSums, blockOff);
  scan_write<<<NBLK, 256, 0, stream>>>(degCnt, blockOff, rowPtr, cursor);
  csr_fill<<<NE / 256, 256, 0, stream>>>(ei, cursor, csrSrc);

  // layer 0
  gather_agg<<<NN / 4, 256, 0, stream>>>(xb, csrSrc, rowPtr, degCnt, msgB);
  node_gemm<<<(NN + 255) / 256, 256, 0, stream>>>(msgB, xb, swz, b0, h0b);

  // layer 1
  gather_agg<<<NN / 4, 256, 0, stream>>>(h0b, csrSrc, rowPtr, degCnt, msgB);
  node_gemm<<<(NN + 255) / 256, 256, 0, stream>>>(msgB, h0b, swz + 32768, b1, h1b);

  // edge classifier
  edge_mlp<<<NE / 128, 256, 0, stream>>>(h1b, ei, ea, swz + 65536, swz + 102400,
                                         Wc3, bc1, bc2, bc3, out);
}

// Round 4
// 859.331 us; speedup vs baseline: 6.7952x; 1.1226x over previous
//
#include <hip/hip_runtime.h>
#include <hip/hip_bf16.h>
#include <math.h>

#define NN 100000
#define NE 1600000
#define NBLK 391   // ceil(NN/256)
#define ZS 296     // z-buffer row stride bytes (74 words, bank-stride 10 -> ~conflict-free)
// dims: D_IN = HID = 128, E_CH = 16

typedef __bf16 bf16x8 __attribute__((ext_vector_type(8)));
typedef float f32x4 __attribute__((ext_vector_type(4)));

union BF8 { bf16x8 v; unsigned short u[8]; };

static __device__ __forceinline__ unsigned short f2bf(float f) {
  unsigned int u = __float_as_uint(f);
  unsigned int r = u + 0x7fffu + ((u >> 16) & 1u);   // RNE
  return (unsigned short)(r >> 16);
}
static __device__ __forceinline__ float bf2f(unsigned short b) {
  return __uint_as_float((unsigned int)b << 16);
}
static __device__ __forceinline__ f32x4 zero4() {
  f32x4 z = {0.f, 0.f, 0.f, 0.f}; return z;
}
static __device__ __forceinline__ bf16x8 zerobf8() {
  BF8 t;
  #pragma unroll
  for (int j = 0; j < 8; ++j) t.u[j] = 0;
  return t.v;
}
static __device__ __forceinline__ bf16x8 cvt8(float4 v0, float4 v1, float s) {
  BF8 t;
  t.u[0]=f2bf(v0.x*s); t.u[1]=f2bf(v0.y*s); t.u[2]=f2bf(v0.z*s); t.u[3]=f2bf(v0.w*s);
  t.u[4]=f2bf(v1.x*s); t.u[5]=f2bf(v1.y*s); t.u[6]=f2bf(v1.z*s); t.u[7]=f2bf(v1.w*s);
  return t.v;
}

// ---------------------------------------------------------------------------
// Pre-swizzle weights into MFMA fragment order (bf16):
//   swz[((t*KC + c)*64 + lane)*8 + j] = W[k][n],  k = c*32 + (lane>>4)*8 + j,
//                                                 n = t*16 + (lane&15)
// element regions:
//   [0)      nodeW0 (Wl0|Wr0 stacked, K=256,N=128)   32768
//   [32768)  nodeW1                                   32768
//   [65536)  PQ0 = Wc1 rows   0..127 (K=128,N=128)    16384
//   [81920)  PQ1 = Wc1 rows 128..255 (K=128,N=128)    16384
//   [98304)  Wea = Wc1 rows 256..271 (K=16 pad 32)     4096
//   [102400) Wc2 (K=128,N=64)                          8192
// total 110592
__global__ void prep_swizzle(const float* __restrict__ Wl0, const float* __restrict__ Wr0,
                             const float* __restrict__ Wl1, const float* __restrict__ Wr1,
                             const float* __restrict__ Wc1, const float* __restrict__ Wc2,
                             __hip_bfloat16* __restrict__ swz) {
  int gid = blockIdx.x * 256 + threadIdx.x;
  if (gid >= 110592) return;
  int id = gid;
  const float* A; const float* B = nullptr; int KC, Nc, Ksrc;
  if (id < 32768)        { KC = 8; Nc = 128; Ksrc = 256; A = Wl0; B = Wr0; }
  else if (id < 65536)   { id -= 32768; KC = 8; Nc = 128; Ksrc = 256; A = Wl1; B = Wr1; }
  else if (id < 81920)   { id -= 65536; KC = 4; Nc = 128; Ksrc = 128; A = Wc1; }
  else if (id < 98304)   { id -= 81920; KC = 4; Nc = 128; Ksrc = 128; A = Wc1 + 128 * 128; }
  else if (id < 102400)  { id -= 98304; KC = 1; Nc = 128; Ksrc = 16;  A = Wc1 + 256 * 128; }
  else                   { id -= 102400; KC = 4; Nc = 64;  Ksrc = 128; A = Wc2; }
  int j = id & 7, lane = (id >> 3) & 63, rest = id >> 9;
  int c = rest % KC, t = rest / KC;
  int k = c * 32 + (lane >> 4) * 8 + j;
  int n = t * 16 + (lane & 15);
  float v = 0.f;
  if (k < Ksrc) {
    if (B && k >= 128) v = B[(k - 128) * Nc + n];
    else               v = A[k * Nc + n];
  }
  unsigned short* o = (unsigned short*)swz;
  o[gid] = f2bf(v);
}

// ---------------------------------------------------------------------------
// x (fp32) -> bf16, vectorized
__global__ void x_to_bf16(const float* __restrict__ x, __hip_bfloat16* __restrict__ xb) {
  int i = blockIdx.x * 256 + threadIdx.x;     // one float4 per thread
  float4 v = ((const float4*)x)[i];
  ushort4 p;
  p.x = f2bf(v.x); p.y = f2bf(v.y); p.z = f2bf(v.z); p.w = f2bf(v.w);
  ((ushort4*)xb)[i] = p;
}

// ---------------------------------------------------------------------------
// CSR build: count degrees, scan, fill (src + packed (dst,eid))
__global__ void deg_count(const int* __restrict__ ei, int* __restrict__ degCnt) {
  int e = blockIdx.x * 256 + threadIdx.x;
  atomicAdd(&degCnt[ei[NE + e]], 1);
}

__global__ void scan_block_sums(const int* __restrict__ degCnt, int* __restrict__ blockSums) {
  __shared__ int red[4];
  int i = blockIdx.x * 256 + threadIdx.x;
  int v = (i < NN) ? degCnt[i] : 0;
  #pragma unroll
  for (int off = 32; off; off >>= 1) v += __shfl_down(v, off, 64);
  if ((threadIdx.x & 63) == 0) red[threadIdx.x >> 6] = v;
  __syncthreads();
  if (threadIdx.x == 0) blockSums[blockIdx.x] = red[0] + red[1] + red[2] + red[3];
}

__global__ void scan_partials(const int* __restrict__ blockSums, int* __restrict__ blockOff) {
  __shared__ int lds[512];
  int t = threadIdx.x;
  int v = (t < NBLK) ? blockSums[t] : 0;
  lds[t] = v; __syncthreads();
  #pragma unroll
  for (int off = 1; off < 512; off <<= 1) {
    int a = (t >= off) ? lds[t - off] : 0;
    __syncthreads();
    lds[t] += a;
    __syncthreads();
  }
  if (t < NBLK) blockOff[t] = lds[t] - v;   // exclusive
}

__global__ void scan_write(const int* __restrict__ degCnt, const int* __restrict__ blockOff,
                           int* __restrict__ rowPtr, int* __restrict__ cursor) {
  __shared__ int lds[256];
  int t = threadIdx.x;
  int i = blockIdx.x * 256 + t;
  int v = (i < NN) ? degCnt[i] : 0;
  lds[t] = v; __syncthreads();
  #pragma unroll
  for (int off = 1; off < 256; off <<= 1) {
    int a = (t >= off) ? lds[t - off] : 0;
    __syncthreads();
    lds[t] += a;
    __syncthreads();
  }
  if (i < NN) {
    int excl = blockOff[blockIdx.x] + lds[t] - v;
    rowPtr[i] = excl;
    cursor[i] = excl;
  }
}

__global__ void csr_fill(const int* __restrict__ ei, int* __restrict__ cursor,
                         int* __restrict__ csrSrc, int2* __restrict__ csrDE) {
  int e = blockIdx.x * 256 + threadIdx.x;
  int s = ei[e], d = ei[NE + e];
  int idx = atomicAdd(&cursor[d], 1);
  csrSrc[idx] = s;
  csrDE[idx] = make_int2(d, e);
}

// ---------------------------------------------------------------------------
// gather-mean: msgOut[n] = mean over neighbors s of feat[s]  (bf16 in/out)
// 16 lanes per node (16B each = full 256B row), 16 nodes/block, unroll-4 for MLP.
__global__ __launch_bounds__(256, 8)
void gather_agg(const __hip_bfloat16* __restrict__ xb,
                const int* __restrict__ csrSrc, const int* __restrict__ rowPtr,
                const int* __restrict__ degCnt, __hip_bfloat16* __restrict__ msgOut) {
  int g = threadIdx.x >> 4, c16 = threadIdx.x & 15;
  int n = blockIdx.x * 16 + g;             // grid 6250 x 16 = 100000 exact
  int rp = rowPtr[n], dg = degCnt[n];
  float a[8];
  #pragma unroll
  for (int j = 0; j < 8; ++j) a[j] = 0.f;
  for (int i = 0; i < dg; i += 4) {
    #pragma unroll
    for (int k = 0; k < 4; ++k) {
      int ii = i + k;
      int s = csrSrc[rp + (ii < dg ? ii : dg - 1)];
      uint4 u = *(const uint4*)((const unsigned short*)xb + (size_t)s * 128 + c16 * 8);
      if (ii < dg) {
        a[0] += bf2f((unsigned short)(u.x & 0xffff)); a[1] += bf2f((unsigned short)(u.x >> 16));
        a[2] += bf2f((unsigned short)(u.y & 0xffff)); a[3] += bf2f((unsigned short)(u.y >> 16));
        a[4] += bf2f((unsigned short)(u.z & 0xffff)); a[5] += bf2f((unsigned short)(u.z >> 16));
        a[6] += bf2f((unsigned short)(u.w & 0xffff)); a[7] += bf2f((unsigned short)(u.w >> 16));
      }
    }
  }
  float r = 1.f / fmaxf((float)dg, 1.f);
  uint4 p;
  p.x = (unsigned)f2bf(a[0] * r) | ((unsigned)f2bf(a[1] * r) << 16);
  p.y = (unsigned)f2bf(a[2] * r) | ((unsigned)f2bf(a[3] * r) << 16);
  p.z = (unsigned)f2bf(a[4] * r) | ((unsigned)f2bf(a[5] * r) << 16);
  p.w = (unsigned)f2bf(a[6] * r) | ((unsigned)f2bf(a[7] * r) << 16);
  *(uint4*)((unsigned short*)msgOut + (size_t)n * 128 + c16 * 8) = p;
}

// ---------------------------------------------------------------------------
// node GEMM: h[n] = relu([mean | self[n]] @ [Wl;Wr] + b)   -> bf16 out
__global__ __launch_bounds__(256, 2)
void node_gemm(const __hip_bfloat16* __restrict__ msgB,
               const __hip_bfloat16* __restrict__ selfB16,
               const __hip_bfloat16* __restrict__ swzW, const float* __restrict__ bias,
               __hip_bfloat16* __restrict__ hOut) {
  const int tid = threadIdx.x, w = tid >> 6, lane = tid & 63;
  const int l15 = lane & 15, quad = lane >> 4;
  const int nBase = blockIdx.x * 256 + w * 64;

  int row[4];
  #pragma unroll
  for (int t = 0; t < 4; ++t) {
    int n = nBase + t * 16 + l15;
    if (n > NN - 1) n = NN - 1;
    row[t] = n;
  }

  f32x4 acc[8][4];
  #pragma unroll
  for (int mt = 0; mt < 8; ++mt)
    #pragma unroll
    for (int nt = 0; nt < 4; ++nt) acc[mt][nt] = zero4();

  #pragma unroll
  for (int c = 0; c < 8; ++c) {
    bf16x8 bfr[4];
    if (c < 4) {
      #pragma unroll
      for (int nt = 0; nt < 4; ++nt)
        bfr[nt] = *(const bf16x8*)(msgB + (size_t)row[nt] * 128 + c * 32 + quad * 8);
    } else {
      #pragma unroll
      for (int nt = 0; nt < 4; ++nt)
        bfr[nt] = *(const bf16x8*)(selfB16 + (size_t)row[nt] * 128 + (c - 4) * 32 + quad * 8);
    }
    bf16x8 afr[8];
    #pragma unroll
    for (int mt = 0; mt < 8; ++mt)
      afr[mt] = *(const bf16x8*)(swzW + ((mt * 8 + c) * 64 + lane) * 8);
    #pragma unroll
    for (int mt = 0; mt < 8; ++mt)
      #pragma unroll
      for (int nt = 0; nt < 4; ++nt)
        acc[mt][nt] = __builtin_amdgcn_mfma_f32_16x16x32_bf16(afr[mt], bfr[nt], acc[mt][nt], 0, 0, 0);
  }

  #pragma unroll
  for (int mt = 0; mt < 8; ++mt) {
    const float4 b4 = *(const float4*)(bias + mt * 16 + quad * 4);
    #pragma unroll
    for (int nt = 0; nt < 4; ++nt) {
      int n = nBase + nt * 16 + l15;
      if (n < NN) {
        ushort4 p;
        p.x = f2bf(fmaxf(acc[mt][nt][0] + b4.x, 0.f));
        p.y = f2bf(fmaxf(acc[mt][nt][1] + b4.y, 0.f));
        p.z = f2bf(fmaxf(acc[mt][nt][2] + b4.z, 0.f));
        p.w = f2bf(fmaxf(acc[mt][nt][3] + b4.w, 0.f));
        *(ushort4*)(hOut + (size_t)n * 128 + mt * 16 + quad * 4) = p;
      }
    }
  }
}

// ---------------------------------------------------------------------------
// P/Q GEMM: P[n] = Wc1[0:128]^T h1[n], Q[n] = Wc1[128:256]^T h1[n]  (bf16 out, no bias)
// blockIdx.y selects P (0) or Q (1).
__global__ __launch_bounds__(256, 2)
void pq_gemm(const __hip_bfloat16* __restrict__ h1, const __hip_bfloat16* __restrict__ swzPQ,
             __hip_bfloat16* __restrict__ Pout, __hip_bfloat16* __restrict__ Qout) {
  const __hip_bfloat16* swzW = swzPQ + blockIdx.y * 16384;
  __hip_bfloat16* outp = blockIdx.y ? Qout : Pout;
  const int tid = threadIdx.x, w = tid >> 6, lane = tid & 63;
  const int l15 = lane & 15, quad = lane >> 4;
  const int nBase = blockIdx.x * 256 + w * 64;

  int row[4];
  #pragma unroll
  for (int t = 0; t < 4; ++t) {
    int n = nBase + t * 16 + l15;
    if (n > NN - 1) n = NN - 1;
    row[t] = n;
  }

  f32x4 acc[8][4];
  #pragma unroll
  for (int mt = 0; mt < 8; ++mt)
    #pragma unroll
    for (int nt = 0; nt < 4; ++nt) acc[mt][nt] = zero4();

  #pragma unroll
  for (int c = 0; c < 4; ++c) {
    bf16x8 bfr[4];
    #pragma unroll
    for (int nt = 0; nt < 4; ++nt)
      bfr[nt] = *(const bf16x8*)(h1 + (size_t)row[nt] * 128 + c * 32 + quad * 8);
    bf16x8 afr[8];
    #pragma unroll
    for (int mt = 0; mt < 8; ++mt)
      afr[mt] = *(const bf16x8*)(swzW + ((mt * 4 + c) * 64 + lane) * 8);
    #pragma unroll
    for (int mt = 0; mt < 8; ++mt)
      #pragma unroll
      for (int nt = 0; nt < 4; ++nt)
        acc[mt][nt] = __builtin_amdgcn_mfma_f32_16x16x32_bf16(afr[mt], bfr[nt], acc[mt][nt], 0, 0, 0);
  }

  #pragma unroll
  for (int mt = 0; mt < 8; ++mt) {
    #pragma unroll
    for (int nt = 0; nt < 4; ++nt) {
      int n = nBase + nt * 16 + l15;
      if (n < NN) {
        ushort4 p;
        p.x = f2bf(acc[mt][nt][0]);
        p.y = f2bf(acc[mt][nt][1]);
        p.z = f2bf(acc[mt][nt][2]);
        p.w = f2bf(acc[mt][nt][3]);
        *(ushort4*)(outp + (size_t)n * 128 + mt * 16 + quad * 4) = p;
      }
    }
  }
}

// ---------------------------------------------------------------------------
// edge MLP (CSR order): z1 = relu(P[src]+Q[dst]+Wea^T ea+bc1); z2 = relu(Wc2^T z1+bc2);
// out[eid] = sigmoid(Wc3^T z2 + bc3).
// 4 waves x 32 edges/wave, per-wave private LDS z-buffer, no barriers. 4 blocks/CU.
__global__ __launch_bounds__(256, 4)
void edge_mlp(const __hip_bfloat16* __restrict__ P, const __hip_bfloat16* __restrict__ Q,
              const float* __restrict__ ea,
              const int* __restrict__ csrSrc, const int2* __restrict__ csrDE,
              const __hip_bfloat16* __restrict__ swzWea, const __hip_bfloat16* __restrict__ swzWc2,
              const float* __restrict__ Wc3, const float* __restrict__ bc1,
              const float* __restrict__ bc2, const float* __restrict__ bc3,
              float* __restrict__ out) {
  __shared__ char lds[4 * 32 * ZS];   // 37888 B -> 4 blocks/CU
  const int tid = threadIdx.x, w = tid >> 6, lane = tid & 63;
  const int l15 = lane & 15, quad = lane >> 4;
  const int eBase = blockIdx.x * 128 + w * 32;
  char* zbuf = lds + w * (32 * ZS);

  int srcO[2], dstO[2], eid[2];
  #pragma unroll
  for (int t = 0; t < 2; ++t) {
    int p = eBase + t * 16 + l15;
    srcO[t] = csrSrc[p] * 128;
    int2 de = csrDE[p];
    dstO[t] = de.x * 128;
    eid[t] = de.y;
  }

  // ---- layer 1 MFMA part: Wea^T ea  (K=16 zero-padded to 32)
  f32x4 acc[8][2];
  #pragma unroll
  for (int mt = 0; mt < 8; ++mt)
    #pragma unroll
    for (int nt = 0; nt < 2; ++nt) acc[mt][nt] = zero4();

  bf16x8 bfr[2];
  #pragma unroll
  for (int nt = 0; nt < 2; ++nt) {
    if (quad < 2) {
      const float4* pe = (const float4*)(ea + (size_t)eid[nt] * 16 + quad * 8);
      bfr[nt] = cvt8(pe[0], pe[1], 1.f);
    } else {
      bfr[nt] = zerobf8();
    }
  }
  #pragma unroll
  for (int mt = 0; mt < 8; ++mt) {
    bf16x8 afr = *(const bf16x8*)(swzWea + (mt * 64 + lane) * 8);
    #pragma unroll
    for (int nt = 0; nt < 2; ++nt)
      acc[mt][nt] = __builtin_amdgcn_mfma_f32_16x16x32_bf16(afr, bfr[nt], acc[mt][nt], 0, 0, 0);
  }

  // ---- epilogue 1: z1 = relu(acc + P[src] + Q[dst] + bc1) -> LDS (bf16, stride ZS)
  #pragma unroll
  for (int mt = 0; mt < 8; ++mt) {
    const int cb = mt * 16 + quad * 4;
    const float4 b4 = *(const float4*)(bc1 + cb);
    #pragma unroll
    for (int nt = 0; nt < 2; ++nt) {
      ushort4 pu = *(const ushort4*)(P + srcO[nt] + cb);
      ushort4 qu = *(const ushort4*)(Q + dstO[nt] + cb);
      int er = nt * 16 + l15;
      ushort4 z;
      z.x = f2bf(fmaxf(acc[mt][nt][0] + bf2f(pu.x) + bf2f(qu.x) + b4.x, 0.f));
      z.y = f2bf(fmaxf(acc[mt][nt][1] + bf2f(pu.y) + bf2f(qu.y) + b4.y, 0.f));
      z.z = f2bf(fmaxf(acc[mt][nt][2] + bf2f(pu.z) + bf2f(qu.z) + b4.z, 0.f));
      z.w = f2bf(fmaxf(acc[mt][nt][3] + bf2f(pu.w) + bf2f(qu.w) + b4.w, 0.f));
      *(ushort4*)(zbuf + er * ZS + cb * 2) = z;
    }
  }

  // ---- layer 2: z2^T = Wc2^T @ z1^T  (K=128, 64 out chans)
  f32x4 acc2[4][2];
  #pragma unroll
  for (int mt = 0; mt < 4; ++mt)
    #pragma unroll
    for (int nt = 0; nt < 2; ++nt) acc2[mt][nt] = zero4();

  #pragma unroll
  for (int c = 0; c < 4; ++c) {
    bf16x8 b2[2];
    #pragma unroll
    for (int nt = 0; nt < 2; ++nt)
      b2[nt] = *(const bf16x8*)(zbuf + (nt * 16 + l15) * ZS + (c * 32 + quad * 8) * 2);
    #pragma unroll
    for (int mt = 0; mt < 4; ++mt) {
      bf16x8 afr = *(const bf16x8*)(swzWc2 + ((mt * 4 + c) * 64 + lane) * 8);
      #pragma unroll
      for (int nt = 0; nt < 2; ++nt)
        acc2[mt][nt] = __builtin_amdgcn_mfma_f32_16x16x32_bf16(afr, b2[nt], acc2[mt][nt], 0, 0, 0);
    }
  }

  // ---- epilogue 2: z2 -> LDS rows (bf16, 64 chans, same stride; z1 reads done)
  #pragma unroll
  for (int mt = 0; mt < 4; ++mt) {
    const int cb = mt * 16 + quad * 4;
    const float4 b4 = *(const float4*)(bc2 + cb);
    #pragma unroll
    for (int nt = 0; nt < 2; ++nt) {
      int er = nt * 16 + l15;
      ushort4 z;
      z.x = f2bf(fmaxf(acc2[mt][nt][0] + b4.x, 0.f));
      z.y = f2bf(fmaxf(acc2[mt][nt][1] + b4.y, 0.f));
      z.z = f2bf(fmaxf(acc2[mt][nt][2] + b4.z, 0.f));
      z.w = f2bf(fmaxf(acc2[mt][nt][3] + b4.w, 0.f));
      *(ushort4*)(zbuf + er * ZS + cb * 2) = z;
    }
  }

  // ---- layer 3: lane pair per edge (half-wave split over 64 chans), sigmoid, scatter
  {
    int e = lane & 31, half = lane >> 5;
    float a3 = (half == 0) ? bc3[0] : 0.f;
    #pragma unroll
    for (int k2 = 0; k2 < 16; ++k2) {
      unsigned int u = *(const unsigned int*)(zbuf + e * ZS + half * 64 + k2 * 4);
      float v0 = __uint_as_float(u << 16);
      float v1 = __uint_as_float(u & 0xffff0000u);
      const float2 wv = *(const float2*)(Wc3 + half * 32 + 2 * k2);
      a3 += v0 * wv.x + v1 * wv.y;
    }
    a3 += __shfl_xor(a3, 32);
    if (half == 0) {
      int oe = csrDE[eBase + e].y;
      out[oe] = 1.f / (1.f + __expf(-a3));
    }
  }
}

// ---------------------------------------------------------------------------
extern "C" void kernel_launch(void* const* d_in, const int* in_sizes, int n_in,
                              void* d_out, int out_size, void* d_ws, size_t ws_size,
                              hipStream_t stream) {
  const float* x   = (const float*)d_in[0];
  const int*   ei  = (const int*)d_in[1];
  const float* ea  = (const float*)d_in[2];
  const float* Wl0 = (const float*)d_in[3];
  const float* Wr0 = (const float*)d_in[4];
  const float* b0  = (const float*)d_in[5];
  const float* Wl1 = (const float*)d_in[6];
  const float* Wr1 = (const float*)d_in[7];
  const float* b1  = (const float*)d_in[8];
  const float* Wc1 = (const float*)d_in[9];
  const float* bc1 = (const float*)d_in[10];
  const float* Wc2 = (const float*)d_in[11];
  const float* bc2 = (const float*)d_in[12];
  const float* Wc3 = (const float*)d_in[13];
  const float* bc3 = (const float*)d_in[14];
  float* out = (float*)d_out;

  char* ws = (char*)d_ws;
  int* degCnt    = (int*)(ws + 0);                            //    400,000 B
  int* rowPtr    = (int*)(ws + 400000);                       //    400,000 B
  int* cursor    = (int*)(ws + 800000);                       //    400,000 B
  int* blockSums = (int*)(ws + 1200000);                      //      2,048 B
  int* blockOff  = (int*)(ws + 1202048);                      //      2,048 B
  int* csrSrc    = (int*)(ws + 1204096);                      //  6,400,000 B
  int2* csrDE    = (int2*)(ws + 7604096);                     // 12,800,000 B
  __hip_bfloat16* bufB = (__hip_bfloat16*)(ws + 20404096);    // 25,600,000 B  msgB / P
  __hip_bfloat16* bufC = (__hip_bfloat16*)(ws + 46004096);    // 25,600,000 B  h0 / Q
  __hip_bfloat16* bufD = (__hip_bfloat16*)(ws + 71604096);    // 25,600,000 B  xb / h1
  __hip_bfloat16* swz  = (__hip_bfloat16*)(ws + 97204096);    //    221,184 B
  // total 97,425,280 B
  __hip_bfloat16* msgB = bufB; __hip_bfloat16* Pb = bufB;
  __hip_bfloat16* h0b  = bufC; __hip_bfloat16* Qb = bufC;
  __hip_bfloat16* xb   = bufD; __hip_bfloat16* h1b = bufD;   // xb dead before h1 written

  hipMemsetAsync(degCnt, 0, 400000, stream);
  prep_swizzle<<<432, 256, 0, stream>>>(Wl0, Wr0, Wl1, Wr1, Wc1, Wc2, swz);
  x_to_bf16<<<12500, 256, 0, stream>>>(x, xb);

  // CSR build (dst-sorted edge order, reused by both layers + classifier)
  deg_count<<<NE / 256, 256, 0, stream>>>(ei, degCnt);
  scan_block_sums<<<NBLK, 256, 0, stream>>>(degCnt, blockSums);
  scan_partials<<<1, 512, 0, stream>>>(blockSums, blockOff);
  scan_write<<<NBLK, 256, 0, stream>>>(degCnt, blockOff, rowPtr, cursor);
  csr_fill<<<NE / 256, 256, 0, stream>>>(ei, cursor, csrSrc, csrDE);

  // layer 0
  gather_agg<<<NN / 16, 256, 0, stream>>>(xb, csrSrc, rowPtr, degCnt, msgB);
  node_gemm<<<NBLK, 256, 0, stream>>>(msgB, xb, swz, b0, h0b);

  // layer 1
  gather_agg<<<NN / 16, 256, 0, stream>>>(h0b, csrSrc, rowPtr, degCnt, msgB);
  node_gemm<<<NBLK, 256, 0, stream>>>(msgB, h0b, swz + 32768, b1, h1b);

  // classifier: hoist Wc1 node parts, then per-edge MLP in CSR order
  pq_gemm<<<dim3(NBLK, 2), 256, 0, stream>>>(h1b, swz + 65536, Pb, Qb);
  edge_mlp<<<NE / 128, 256, 0, stream>>>(Pb, Qb, ea, csrSrc, csrDE,
                                         swz + 98304, swz + 102400,
                                         Wc3, bc1, bc2, bc3, out);
}